// Round 6
// baseline (547.163 us; speedup 1.0000x reference)
//
#include <hip/hip_runtime.h>
#include <stdint.h>

typedef int v4i  __attribute__((ext_vector_type(4)));
typedef int v16i __attribute__((ext_vector_type(16)));

#define CAPACITY  65536
#define BATCH     2048
#define KBITS     1024

// ===========================================================================
// MFMA path: dist(q,k) = sumq + sumk - 2*dot(q,k). sumq is constant per query
// row -> drop it; rank by packed ((sumk - 2*dot + 2048)<<16) | key_idx, which
// is exact (0 <= biased dist <= 3072 < 2^16) and reproduces first-max argmax.
// ===========================================================================

// ---- bits (int32 0/1) -> i8 bytes, plus per-row bit count --------------------
__global__ void prep_i8_kernel(const int* __restrict__ in,
                               unsigned char* __restrict__ out8,
                               int* __restrict__ sums) {
    const int row = blockIdx.x, t = threadIdx.x;      // one block per 1024-bit row
    int4 v = reinterpret_cast<const int4*>(in)[(size_t)row * 256 + t];
    uint32_t b = (uint32_t)(v.x & 1)        | ((uint32_t)(v.y & 1) << 8) |
                 ((uint32_t)(v.z & 1) << 16) | ((uint32_t)(v.w & 1) << 24);
    reinterpret_cast<uint32_t*>(out8)[(size_t)row * 256 + t] = b;
    int s = (v.x & 1) + (v.y & 1) + (v.z & 1) + (v.w & 1);
    for (int off = 32; off; off >>= 1) s += __shfl_xor(s, off, 64);
    __shared__ int ws4[4];
    if ((t & 63) == 0) ws4[t >> 6] = s;
    __syncthreads();
    if (t == 0) sums[row] = ws4[0] + ws4[1] + ws4[2] + ws4[3];
}

__global__ void init_best_kernel(uint32_t* __restrict__ best) {
    best[blockIdx.x * 256 + threadIdx.x] = 0xFFFFFFFFu;
}

// swizzled 16B-chunk index within a [rows][64B] LDS tile: bijective
// (upper-triangular bit mix), spreads rows across banks -> conflict floor on
// both ds_write_b128 (staging) and ds_read_b128 (frag reads).
__device__ __forceinline__ int swzi(int row, int chunk) {
    return ((row << 2) | chunk) ^ (row & 7);
}

// ---- GEMM + fused argmin. Block tile 128(M) x 256(N), K-step 64, 4 waves as
// 2x2, each wave 2x4 tiles of 32x32x32_i8. Double-buffered LDS, reg-staged
// (loads issued at phase start, ds_write after compute = async-stage split),
// one barrier per K-step.
__launch_bounds__(256, 2)
__global__ void gemm_scan_kernel(const unsigned char* __restrict__ qi8,
                                 const unsigned char* __restrict__ ki8,
                                 const int* __restrict__ sumk,
                                 uint32_t* __restrict__ best) {
    __shared__ uint4 sA[2][512];    // [buf][128 rows x 4 chunks] = 16 KB
    __shared__ uint4 sB[2][1024];   // [buf][256 rows x 4 chunks] = 32 KB

    const int t    = threadIdx.x;
    const int lane = t & 63, wid = t >> 6;
    const int wr   = wid >> 1, wc = wid & 1;      // wave grid 2x2
    const int ln   = lane & 31, kh = lane >> 5;   // mfma row/col, k-half
    const int mtile = blockIdx.x & 15, ntile = blockIdx.x >> 4;
    const int m0 = mtile * 128, n0 = ntile * 256;

    v16i acc[2][4];
#pragma unroll
    for (int rt = 0; rt < 2; ++rt)
#pragma unroll
        for (int ct = 0; ct < 4; ++ct)
#pragma unroll
            for (int e = 0; e < 16; ++e) acc[rt][ct][e] = 0;

    uint4 ra[2], rb[4];
    const int arow = (lane >> 2), achk = (lane & 3);

    auto LOAD = [&](int kc) {                     // global -> regs (coalesced 64B groups)
#pragma unroll
        for (int i = 0; i < 2; ++i) {
            int row = wid * 32 + i * 16 + arow;
            ra[i] = *reinterpret_cast<const uint4*>(
                qi8 + (size_t)(m0 + row) * KBITS + kc + achk * 16);
        }
#pragma unroll
        for (int i = 0; i < 4; ++i) {
            int row = wid * 64 + i * 16 + arow;
            rb[i] = *reinterpret_cast<const uint4*>(
                ki8 + (size_t)(n0 + row) * KBITS + kc + achk * 16);
        }
    };
    auto STORE = [&](int b) {                     // regs -> LDS (swizzled)
#pragma unroll
        for (int i = 0; i < 2; ++i)
            sA[b][swzi(wid * 32 + i * 16 + arow, achk)] = ra[i];
#pragma unroll
        for (int i = 0; i < 4; ++i)
            sB[b][swzi(wid * 64 + i * 16 + arow, achk)] = rb[i];
    };

    LOAD(0);
    STORE(0);
    __syncthreads();

    for (int s = 0; s < 16; ++s) {                // 16 K-steps of 64
        const int p = s & 1;
        if (s < 15) LOAD((s + 1) * 64);           // in flight under compute

#pragma unroll
        for (int km = 0; km < 2; ++km) {          // two K=32 mfma per step
            uint4 af[2], bf[4];
#pragma unroll
            for (int rt = 0; rt < 2; ++rt)
                af[rt] = sA[p][swzi(wr * 64 + rt * 32 + ln, km * 2 + kh)];
#pragma unroll
            for (int ct = 0; ct < 4; ++ct)
                bf[ct] = sB[p][swzi(wc * 128 + ct * 32 + ln, km * 2 + kh)];
#pragma unroll
            for (int rt = 0; rt < 2; ++rt)
#pragma unroll
                for (int ct = 0; ct < 4; ++ct)
                    acc[rt][ct] = __builtin_amdgcn_mfma_i32_32x32x32_i8(
                        *(v4i*)&af[rt], *(v4i*)&bf[ct], acc[rt][ct], 0, 0, 0);
        }

        if (s < 15) {
            STORE(p ^ 1);                         // other buffer; readers of it
            __syncthreads();                      // passed the previous barrier
        }
    }

    // ---- epilogue: packed argmin, exact tie-break -------------------------
    int sk[4];
#pragma unroll
    for (int ct = 0; ct < 4; ++ct) sk[ct] = sumk[n0 + wc * 128 + ct * 32 + ln];

#pragma unroll
    for (int rt = 0; rt < 2; ++rt) {
#pragma unroll
        for (int r = 0; r < 16; ++r) {
            // verified C/D map: col = lane&31, row = (r&3)+8*(r>>2)+4*(lane>>5)
            const int qrow = m0 + wr * 64 + rt * 32 + (r & 3) + 8 * (r >> 2) + 4 * kh;
            uint32_t bmin = 0xFFFFFFFFu;
#pragma unroll
            for (int ct = 0; ct < 4; ++ct) {
                uint32_t dist = (uint32_t)(sk[ct] - 2 * acc[rt][ct][r] + 2048);
                uint32_t col  = (uint32_t)(n0 + wc * 128 + ct * 32 + ln);
                bmin = min(bmin, (dist << 16) | col);
            }
#pragma unroll
            for (int off = 1; off < 32; off <<= 1)   // reduce over 32 cols (half-wave)
                bmin = min(bmin, (uint32_t)__shfl_xor((int)bmin, off, 64));
            if (ln == 0) atomicMin(&best[qrow], bmin);
        }
    }
}

// ---- best[q] -> gather values row ------------------------------------------
__global__ void finalize_kernel(const uint32_t* __restrict__ best,
                                const float* __restrict__ values,
                                float* __restrict__ out) {
    const int qy  = blockIdx.x;
    const int idx = (int)(best[qy] & 0xFFFFu);
    const float4* v4 = reinterpret_cast<const float4*>(values) + (size_t)idx * 256;
    float4* o4 = reinterpret_cast<float4*>(out) + (size_t)qy * 256;
    o4[threadIdx.x] = v4[threadIdx.x];
}

// ===========================================================================
// Fallback (round-5 VALU scan, passed at 401 us) if ws_size can't hold i8 keys
// ===========================================================================
#define KCHUNK 256
#define NSPLIT (CAPACITY / KCHUNK)

__device__ __forceinline__ uint32_t pack_word(const int4* __restrict__ p) {
    uint32_t word = 0;
#pragma unroll
    for (int j = 0; j < 8; ++j) {
        int4 v = p[j];
        word |= (uint32_t)(v.x & 1) << (4 * j + 0);
        word |= (uint32_t)(v.y & 1) << (4 * j + 1);
        word |= (uint32_t)(v.z & 1) << (4 * j + 2);
        word |= (uint32_t)(v.w & 1) << (4 * j + 3);
    }
    return word;
}

__global__ void pack_bits_kernel(const int* __restrict__ in,
                                 uint32_t* __restrict__ out, int nwords) {
    int w = blockIdx.x * blockDim.x + threadIdx.x;
    if (w >= nwords) return;
    out[w] = pack_word(reinterpret_cast<const int4*>(in) + (size_t)w * 8);
}

__launch_bounds__(256, 4)
__global__ void scan_kernel(const uint32_t* __restrict__ qpack,
                            const uint32_t* __restrict__ kpack,
                            uint32_t* __restrict__ best) {
    const int t      = threadIdx.x;
    const int lane   = t & 63;
    const int wid    = t >> 6;
    const int ksplit = blockIdx.x & (NSPLIT - 1);
    const int qgb    = blockIdx.x >> 8;
    const int query  = qgb * 256 + wid * 64 + lane;

    uint32_t q[32];
    const uint4* qp4 = reinterpret_cast<const uint4*>(qpack + (size_t)query * 32);
#pragma unroll
    for (int j = 0; j < 8; ++j) {
        uint4 v = qp4[j];
        q[4 * j + 0] = v.x; q[4 * j + 1] = v.y;
        q[4 * j + 2] = v.z; q[4 * j + 3] = v.w;
    }
    uint32_t b = 0xFFFFFFFFu;
    const int k0 = ksplit * KCHUNK;
#pragma unroll 2
    for (int k = k0; k < k0 + KCHUNK; ++k) {
        const uint4* kw4 = reinterpret_cast<const uint4*>(kpack + (size_t)k * 32);
        uint32_t dist = 0;
#pragma unroll
        for (int j = 0; j < 8; ++j) {
            uint4 kv = kw4[j];
            dist += __popc(kv.x ^ q[4 * j + 0]);
            dist += __popc(kv.y ^ q[4 * j + 1]);
            dist += __popc(kv.z ^ q[4 * j + 2]);
            dist += __popc(kv.w ^ q[4 * j + 3]);
        }
        b = min(b, (dist << 16) | (uint32_t)k);
    }
    atomicMin(&best[query], b);
}

// ===========================================================================
extern "C" void kernel_launch(void* const* d_in, const int* in_sizes, int n_in,
                              void* d_out, int out_size, void* d_ws, size_t ws_size,
                              hipStream_t stream) {
    const int*   query  = (const int*)d_in[0];   // [2048, 1024] int32 0/1
    const int*   keys   = (const int*)d_in[1];   // [65536, 1024] int32 0/1
    const float* values = (const float*)d_in[2]; // [65536, 1024] f32
    float*       out    = (float*)d_out;         // [2048, 1024] f32
    char* ws = (char*)d_ws;

    const size_t need = 2097152ULL + 67108864ULL + 262144ULL + 8192ULL + 8192ULL;
    if (ws_size >= need) {
        unsigned char* qi8 = (unsigned char*)ws;                 // 2 MB
        unsigned char* ki8 = (unsigned char*)(ws + 2097152);     // 64 MB
        int* sumk = (int*)(ws + 2097152 + 67108864);             // 256 KB
        int* sumq = (int*)(ws + 2097152 + 67108864 + 262144);    // 8 KB (unused)
        uint32_t* best = (uint32_t*)(ws + 2097152 + 67108864 + 262144 + 8192);

        init_best_kernel<<<BATCH / 256, 256, 0, stream>>>(best);
        prep_i8_kernel<<<BATCH,    256, 0, stream>>>(query, qi8, sumq);
        prep_i8_kernel<<<CAPACITY, 256, 0, stream>>>(keys,  ki8, sumk);
        gemm_scan_kernel<<<16 * 256, 256, 0, stream>>>(qi8, ki8, sumk, best);
        finalize_kernel<<<BATCH, 256, 0, stream>>>(best, values, out);
    } else {
        uint32_t* qpack = (uint32_t*)ws;                         // 256 KB
        uint32_t* kpack = (uint32_t*)(ws + 262144);              // 8 MB
        uint32_t* best  = (uint32_t*)(ws + 262144 + 8388608);    // 8 KB

        init_best_kernel<<<BATCH / 256, 256, 0, stream>>>(best);
        pack_bits_kernel<<<BATCH * 32 / 256, 256, 0, stream>>>(query, qpack, BATCH * 32);
        pack_bits_kernel<<<CAPACITY * 32 / 256, 256, 0, stream>>>(keys, kpack, CAPACITY * 32);
        scan_kernel<<<8 * NSPLIT, 256, 0, stream>>>(qpack, kpack, best);
        finalize_kernel<<<BATCH, 256, 0, stream>>>(best, values, out);
    }
}

// Round 7
// 273.332 us; speedup vs baseline: 2.0018x; 2.0018x over previous
//
#include <hip/hip_runtime.h>
#include <stdint.h>

typedef int v4i  __attribute__((ext_vector_type(4)));
typedef int v16i __attribute__((ext_vector_type(16)));

#define CAPACITY  65536
#define BATCH     2048
#define KBITS     1024
#define NSTEP     16      // K-steps of 64 bytes
#define NBUF      3       // triple-buffered LDS

// ===========================================================================
// MFMA path: dist(q,k) = sumq + sumk - 2*dot(q,k). sumq is constant per query
// row -> drop it; rank by packed ((sumk - 2*dot + 2048)<<16) | key_idx, exact
// (0 <= biased dist <= 3072 < 2^16), reproduces first-max argmax.
// ===========================================================================

// ---- bits (int32 0/1) -> i8 bytes, plus per-row bit count ------------------
__global__ void prep_i8_kernel(const int* __restrict__ in,
                               unsigned char* __restrict__ out8,
                               int* __restrict__ sums) {
    const int row = blockIdx.x, t = threadIdx.x;      // one block per 1024-bit row
    int4 v = reinterpret_cast<const int4*>(in)[(size_t)row * 256 + t];
    uint32_t b = (uint32_t)(v.x & 1)        | ((uint32_t)(v.y & 1) << 8) |
                 ((uint32_t)(v.z & 1) << 16) | ((uint32_t)(v.w & 1) << 24);
    reinterpret_cast<uint32_t*>(out8)[(size_t)row * 256 + t] = b;
    int s = (v.x & 1) + (v.y & 1) + (v.z & 1) + (v.w & 1);
    for (int off = 32; off; off >>= 1) s += __shfl_xor(s, off, 64);
    __shared__ int ws4[4];
    if ((t & 63) == 0) ws4[t >> 6] = s;
    __syncthreads();
    if (t == 0) sums[row] = ws4[0] + ws4[1] + ws4[2] + ws4[3];
}

__global__ void init_best_kernel(uint32_t* __restrict__ best) {
    best[blockIdx.x * 256 + threadIdx.x] = 0xFFFFFFFFu;
}

// Involutive 16B-chunk swizzle within a [rows][64B] tile (idx = row*4+chunk):
// XOR low 3 bits with untouched higher bits -> self-inverse, and for a fixed
// chunk, 8 consecutive rows map to 8 distinct (idx%8) bank groups (read floor).
// Self-inverse => global_load_lds sources can be pre-swizzled with the SAME
// function while LDS stays linear in lane order (rule #21 / m173 pattern).
__device__ __forceinline__ int swz(int idx) { return idx ^ ((idx >> 3) & 7); }

// ---- GEMM + fused argmin ---------------------------------------------------
// Block tile 128(M) x 256(N), K-step 64 B, 4 waves as 2x2, each wave 2x4
// tiles of mfma_i32_32x32x32_i8. Staging via global_load_lds width-16
// (no reg roundtrip), triple-buffered LDS, raw s_barrier with COUNTED
// vmcnt(6): the 6 loads for k(s+2) stay in flight across the barrier.
__launch_bounds__(256, 2)
__global__ void gemm_scan_kernel(const unsigned char* __restrict__ qi8,
                                 const unsigned char* __restrict__ ki8,
                                 const int* __restrict__ sumk,
                                 uint32_t* __restrict__ best) {
    __shared__ uint4 sA[NBUF][512];    // 128 rows x 4 chunks  -> 24 KB
    __shared__ uint4 sB[NBUF][1024];   // 256 rows x 4 chunks  -> 48 KB

    const int t    = threadIdx.x;
    const int lane = t & 63, wid = t >> 6;
    const int wr   = wid >> 1, wc = wid & 1;      // wave grid 2x2
    const int ln   = lane & 31, kh = lane >> 5;   // mfma col/row, k-half

    // XCD-pinned tile order: xcd = blockIdx&7 owns ntiles [xcd*32, xcd*32+32),
    // mtile innermost -> per-XCD L2 set ~= 4 B-tiles (1 MB) + qi8 (2 MB) < 4 MB.
    const int b     = blockIdx.x;
    const int slot  = b >> 3;
    const int ntile = (b & 7) * 32 + (slot >> 4);
    const int mtile = slot & 15;
    const int m0 = mtile * 128, n0 = ntile * 256;

    // Pre-swizzled per-lane global sources: LDS slot p holds global chunk
    // swz(p); since swz is an involution, reading LDS[swz(row*4+chunk)]
    // yields global (row, chunk).
    const unsigned char* aSrc[2];
    const unsigned char* bSrc[4];
#pragma unroll
    for (int i = 0; i < 2; ++i) {
        int idx = swz(wid * 128 + i * 64 + lane);
        aSrc[i] = qi8 + (size_t)(m0 + (idx >> 2)) * KBITS + (idx & 3) * 16;
    }
#pragma unroll
    for (int i = 0; i < 4; ++i) {
        int idx = swz(wid * 256 + i * 64 + lane);
        bSrc[i] = ki8 + (size_t)(n0 + (idx >> 2)) * KBITS + (idx & 3) * 16;
    }

    // 6 global_load_lds per wave per K-step (2 A + 4 B), 16 B each
    auto STAGE = [&](int buf, int kc) {
#pragma unroll
        for (int i = 0; i < 2; ++i)
            __builtin_amdgcn_global_load_lds(
                (const __attribute__((address_space(1))) void*)(aSrc[i] + kc),
                (__attribute__((address_space(3))) void*)&sA[buf][wid * 128 + i * 64],
                16, 0, 0);
#pragma unroll
        for (int i = 0; i < 4; ++i)
            __builtin_amdgcn_global_load_lds(
                (const __attribute__((address_space(1))) void*)(bSrc[i] + kc),
                (__attribute__((address_space(3))) void*)&sB[buf][wid * 256 + i * 64],
                16, 0, 0);
    };

    // fragment byte-slot offsets (K-invariant; all indices static after unroll)
    int offA[2][2], offB[2][4];
#pragma unroll
    for (int km = 0; km < 2; ++km) {
#pragma unroll
        for (int rt = 0; rt < 2; ++rt)
            offA[km][rt] = swz((wr * 64 + rt * 32 + ln) * 4 + km * 2 + kh);
#pragma unroll
        for (int ct = 0; ct < 4; ++ct)
            offB[km][ct] = swz((wc * 128 + ct * 32 + ln) * 4 + km * 2 + kh);
    }

    v16i acc[2][4];
#pragma unroll
    for (int rt = 0; rt < 2; ++rt)
#pragma unroll
        for (int ct = 0; ct < 4; ++ct)
#pragma unroll
            for (int e = 0; e < 16; ++e) acc[rt][ct][e] = 0;

    // prologue: prime 2 tiles; wait only for tile 0 (tile 1 stays in flight)
    STAGE(0, 0);
    STAGE(1, 64);
    asm volatile("s_waitcnt vmcnt(6)" ::: "memory");
    __builtin_amdgcn_s_barrier();

    int buf = 0;
    for (int s = 0; s < NSTEP; ++s) {
        if (s + 2 < NSTEP) {                       // issue k(s+2); in flight
            int nb = buf + 2; if (nb >= NBUF) nb -= NBUF;
            STAGE(nb, (s + 2) * 64);
        }

        uint4 af[2][2], bf[2][4];
#pragma unroll
        for (int km = 0; km < 2; ++km) {
#pragma unroll
            for (int rt = 0; rt < 2; ++rt) af[km][rt] = sA[buf][offA[km][rt]];
#pragma unroll
            for (int ct = 0; ct < 4; ++ct) bf[km][ct] = sB[buf][offB[km][ct]];
        }
#pragma unroll
        for (int km = 0; km < 2; ++km)
#pragma unroll
            for (int rt = 0; rt < 2; ++rt)
#pragma unroll
                for (int ct = 0; ct < 4; ++ct)
                    acc[rt][ct] = __builtin_amdgcn_mfma_i32_32x32x32_i8(
                        *(v4i*)&af[km][rt], *(v4i*)&bf[km][ct], acc[rt][ct], 0, 0, 0);

        if (s < NSTEP - 1) {
            // counted drain: k(s+1)'s 6 loads must be done; k(s+2)'s 6 stay
            // in flight. lgkmcnt(0): this wave's ds_reads done before others
            // may overwrite buf (staged at step s+1 into buf[(s+3)%3]=buf).
            if (s < NSTEP - 2)
                asm volatile("s_waitcnt vmcnt(6) lgkmcnt(0)" ::: "memory");
            else
                asm volatile("s_waitcnt vmcnt(0) lgkmcnt(0)" ::: "memory");
            __builtin_amdgcn_s_barrier();
        }
        buf = buf + 1 == NBUF ? 0 : buf + 1;
    }

    // ---- epilogue: packed argmin, exact tie-break (verified round 6) ------
    int sk[4];
#pragma unroll
    for (int ct = 0; ct < 4; ++ct) sk[ct] = sumk[n0 + wc * 128 + ct * 32 + ln];

#pragma unroll
    for (int rt = 0; rt < 2; ++rt) {
#pragma unroll
        for (int r = 0; r < 16; ++r) {
            // verified C/D map: col = lane&31, row = (r&3)+8*(r>>2)+4*(lane>>5)
            const int qrow = m0 + wr * 64 + rt * 32 + (r & 3) + 8 * (r >> 2) + 4 * kh;
            uint32_t bmin = 0xFFFFFFFFu;
#pragma unroll
            for (int ct = 0; ct < 4; ++ct) {
                uint32_t dist = (uint32_t)(sk[ct] - 2 * acc[rt][ct][r] + 2048);
                uint32_t col  = (uint32_t)(n0 + wc * 128 + ct * 32 + ln);
                bmin = min(bmin, (dist << 16) | col);
            }
#pragma unroll
            for (int off = 1; off < 32; off <<= 1)   // reduce over 32 cols
                bmin = min(bmin, (uint32_t)__shfl_xor((int)bmin, off, 64));
            if (ln == 0) atomicMin(&best[qrow], bmin);
        }
    }
}

// ---- best[q] -> gather values row ------------------------------------------
__global__ void finalize_kernel(const uint32_t* __restrict__ best,
                                const float* __restrict__ values,
                                float* __restrict__ out) {
    const int qy  = blockIdx.x;
    const int idx = (int)(best[qy] & 0xFFFFu);
    const float4* v4 = reinterpret_cast<const float4*>(values) + (size_t)idx * 256;
    float4* o4 = reinterpret_cast<float4*>(out) + (size_t)qy * 256;
    o4[threadIdx.x] = v4[threadIdx.x];
}

// ===========================================================================
// Fallback (round-5 VALU scan, 401 us) if ws_size can't hold i8 keys
// ===========================================================================
#define KCHUNK 256
#define NSPLIT (CAPACITY / KCHUNK)

__device__ __forceinline__ uint32_t pack_word(const int4* __restrict__ p) {
    uint32_t word = 0;
#pragma unroll
    for (int j = 0; j < 8; ++j) {
        int4 v = p[j];
        word |= (uint32_t)(v.x & 1) << (4 * j + 0);
        word |= (uint32_t)(v.y & 1) << (4 * j + 1);
        word |= (uint32_t)(v.z & 1) << (4 * j + 2);
        word |= (uint32_t)(v.w & 1) << (4 * j + 3);
    }
    return word;
}

__global__ void pack_bits_kernel(const int* __restrict__ in,
                                 uint32_t* __restrict__ out, int nwords) {
    int w = blockIdx.x * blockDim.x + threadIdx.x;
    if (w >= nwords) return;
    out[w] = pack_word(reinterpret_cast<const int4*>(in) + (size_t)w * 8);
}

__launch_bounds__(256, 4)
__global__ void scan_kernel(const uint32_t* __restrict__ qpack,
                            const uint32_t* __restrict__ kpack,
                            uint32_t* __restrict__ best) {
    const int t      = threadIdx.x;
    const int lane   = t & 63;
    const int wid    = t >> 6;
    const int ksplit = blockIdx.x & (NSPLIT - 1);
    const int qgb    = blockIdx.x >> 8;
    const int query  = qgb * 256 + wid * 64 + lane;

    uint32_t q[32];
    const uint4* qp4 = reinterpret_cast<const uint4*>(qpack + (size_t)query * 32);
#pragma unroll
    for (int j = 0; j < 8; ++j) {
        uint4 v = qp4[j];
        q[4 * j + 0] = v.x; q[4 * j + 1] = v.y;
        q[4 * j + 2] = v.z; q[4 * j + 3] = v.w;
    }
    uint32_t bst = 0xFFFFFFFFu;
    const int k0 = ksplit * KCHUNK;
#pragma unroll 2
    for (int k = k0; k < k0 + KCHUNK; ++k) {
        const uint4* kw4 = reinterpret_cast<const uint4*>(kpack + (size_t)k * 32);
        uint32_t dist = 0;
#pragma unroll
        for (int j = 0; j < 8; ++j) {
            uint4 kv = kw4[j];
            dist += __popc(kv.x ^ q[4 * j + 0]);
            dist += __popc(kv.y ^ q[4 * j + 1]);
            dist += __popc(kv.z ^ q[4 * j + 2]);
            dist += __popc(kv.w ^ q[4 * j + 3]);
        }
        bst = min(bst, (dist << 16) | (uint32_t)k);
    }
    atomicMin(&best[query], bst);
}

// ===========================================================================
extern "C" void kernel_launch(void* const* d_in, const int* in_sizes, int n_in,
                              void* d_out, int out_size, void* d_ws, size_t ws_size,
                              hipStream_t stream) {
    const int*   query  = (const int*)d_in[0];   // [2048, 1024] int32 0/1
    const int*   keys   = (const int*)d_in[1];   // [65536, 1024] int32 0/1
    const float* values = (const float*)d_in[2]; // [65536, 1024] f32
    float*       out    = (float*)d_out;         // [2048, 1024] f32
    char* ws = (char*)d_ws;

    const size_t need = 2097152ULL + 67108864ULL + 262144ULL + 8192ULL + 8192ULL;
    if (ws_size >= need) {
        unsigned char* qi8 = (unsigned char*)ws;                 // 2 MB
        unsigned char* ki8 = (unsigned char*)(ws + 2097152);     // 64 MB
        int* sumk = (int*)(ws + 2097152 + 67108864);             // 256 KB
        int* sumq = (int*)(ws + 2097152 + 67108864 + 262144);    // 8 KB (unused)
        uint32_t* best = (uint32_t*)(ws + 2097152 + 67108864 + 262144 + 8192);

        init_best_kernel<<<BATCH / 256, 256, 0, stream>>>(best);
        prep_i8_kernel<<<BATCH,    256, 0, stream>>>(query, qi8, sumq);
        prep_i8_kernel<<<CAPACITY, 256, 0, stream>>>(keys,  ki8, sumk);
        gemm_scan_kernel<<<16 * 256, 256, 0, stream>>>(qi8, ki8, sumk, best);
        finalize_kernel<<<BATCH, 256, 0, stream>>>(best, values, out);
    } else {
        uint32_t* qpack = (uint32_t*)ws;                         // 256 KB
        uint32_t* kpack = (uint32_t*)(ws + 262144);              // 8 MB
        uint32_t* best  = (uint32_t*)(ws + 262144 + 8388608);    // 8 KB

        init_best_kernel<<<BATCH / 256, 256, 0, stream>>>(best);
        pack_bits_kernel<<<BATCH * 32 / 256, 256, 0, stream>>>(query, qpack, BATCH * 32);
        pack_bits_kernel<<<CAPACITY * 32 / 256, 256, 0, stream>>>(keys, kpack, CAPACITY * 32);
        scan_kernel<<<8 * NSPLIT, 256, 0, stream>>>(qpack, kpack, best);
        finalize_kernel<<<BATCH, 256, 0, stream>>>(best, values, out);
    }
}

// Round 8
// 265.446 us; speedup vs baseline: 2.0613x; 1.0297x over previous
//
#include <hip/hip_runtime.h>
#include <stdint.h>

typedef int v4i  __attribute__((ext_vector_type(4)));
typedef int v16i __attribute__((ext_vector_type(16)));

#define CAPACITY  65536
#define BATCH     2048
#define KBITS     1024
#define NSTEP     16      // K-steps of 64 bytes
#define NBUF      3       // triple-buffered B LDS

// ===========================================================================
// MFMA path: dist(q,k) = sumq + sumk - 2*dot(q,k). sumq is constant per query
// row -> drop it; rank by packed ((sumk - 2*dot + 2048)<<16) | key_idx, exact
// (0 <= biased dist <= 3072 < 2^16), reproduces first-max argmax.
// A (queries) is read per-fragment straight from a blocked-transposed global
// layout (L1/L2-resident); only B (keys) goes through LDS.
// ===========================================================================

// ---- queries: bits -> i8, blocked-transposed qT[k/16][m][16] ----------------
// Fragment load for mfma A-operand (lane l: row=l&31, k=(l>>5)*16..+16) is
// then one coalesced global_load_dwordx4 (32 lanes x contiguous 16B).
__global__ void prep_qT_kernel(const int* __restrict__ in,
                               uint32_t* __restrict__ outT) {
    const int row = blockIdx.x, t = threadIdx.x;   // t covers bits 4t..4t+3
    int4 v = reinterpret_cast<const int4*>(in)[(size_t)row * 256 + t];
    uint32_t b = (uint32_t)(v.x & 1)        | ((uint32_t)(v.y & 1) << 8) |
                 ((uint32_t)(v.z & 1) << 16) | ((uint32_t)(v.w & 1) << 24);
    // kc = t>>2 (16-byte k-chunk), u32 slot within chunk = t&3
    outT[(size_t)(t >> 2) * (BATCH * 4) + (size_t)row * 4 + (t & 3)] = b;
}

// ---- keys: bits -> i8 row-major, plus per-row bit count ---------------------
__global__ void prep_i8_kernel(const int* __restrict__ in,
                               unsigned char* __restrict__ out8,
                               int* __restrict__ sums) {
    const int row = blockIdx.x, t = threadIdx.x;
    int4 v = reinterpret_cast<const int4*>(in)[(size_t)row * 256 + t];
    uint32_t b = (uint32_t)(v.x & 1)        | ((uint32_t)(v.y & 1) << 8) |
                 ((uint32_t)(v.z & 1) << 16) | ((uint32_t)(v.w & 1) << 24);
    reinterpret_cast<uint32_t*>(out8)[(size_t)row * 256 + t] = b;
    int s = (v.x & 1) + (v.y & 1) + (v.z & 1) + (v.w & 1);
    for (int off = 32; off; off >>= 1) s += __shfl_xor(s, off, 64);
    __shared__ int ws4[4];
    if ((t & 63) == 0) ws4[t >> 6] = s;
    __syncthreads();
    if (t == 0) sums[row] = ws4[0] + ws4[1] + ws4[2] + ws4[3];
}

__global__ void init_best_kernel(uint32_t* __restrict__ best) {
    best[blockIdx.x * 256 + threadIdx.x] = 0xFFFFFFFFu;
}

// Involutive 16B-chunk swizzle within a [rows][64B] tile (idx = row*4+chunk):
// self-inverse, spreads consecutive rows across bank groups (read floor).
// global_load_lds sources pre-swizzled with the SAME function, LDS linear.
__device__ __forceinline__ int swz(int idx) { return idx ^ ((idx >> 3) & 7); }

// ---- GEMM + fused argmin ---------------------------------------------------
// Block tile 128(M) x 256(N), K-step 64 B, 4 waves as 2x2, each wave 2x4
// tiles of mfma_i32_32x32x32_i8. A fragments direct from global (qT);
// B staged via global_load_lds into triple-buffered LDS with counted vmcnt.
// Per step: af loads issued FIRST (so compiler's af-wait vmcnt(4) leaves the
// 4 B-stage loads of k(s+2) in flight), then STAGE, ds_reads, and two
// setprio-wrapped 8-MFMA clusters (T5: role-split for the CU scheduler).
__launch_bounds__(256, 2)
__global__ void gemm_scan_kernel(const uint4* __restrict__ aT4,
                                 const unsigned char* __restrict__ ki8,
                                 const int* __restrict__ sumk,
                                 uint32_t* __restrict__ best) {
    __shared__ uint4 sB[NBUF][1024];   // 256 rows x 4 chunks -> 48 KB

    const int t    = threadIdx.x;
    const int lane = t & 63, wid = t >> 6;
    const int wr   = wid >> 1, wc = wid & 1;      // wave grid 2x2
    const int ln   = lane & 31, kh = lane >> 5;   // mfma row, k-half

    // XCD-pinned tile order: xcd = blockIdx&7 owns 32 ntiles, mtile innermost
    const int b     = blockIdx.x;
    const int slot  = b >> 3;
    const int ntile = (b & 7) * 32 + (slot >> 4);
    const int mtile = slot & 15;
    const int m0 = mtile * 128, n0 = ntile * 256;

    // B staging sources, pre-swizzled (swz is an involution; LDS dest linear)
    const unsigned char* bSrc[4];
#pragma unroll
    for (int i = 0; i < 4; ++i) {
        int idx = swz(wid * 256 + i * 64 + lane);
        bSrc[i] = ki8 + (size_t)(n0 + (idx >> 2)) * KBITS + (idx & 3) * 16;
    }
    auto STAGE_B = [&](int buf, int kc) {          // 4 x global_load_lds(16B)
#pragma unroll
        for (int i = 0; i < 4; ++i)
            __builtin_amdgcn_global_load_lds(
                (const __attribute__((address_space(1))) void*)(bSrc[i] + kc),
                (__attribute__((address_space(3))) void*)&sB[buf][wid * 256 + i * 64],
                16, 0, 0);
    };

    // B fragment LDS offsets (K-invariant)
    int offB[2][4];
#pragma unroll
    for (int km = 0; km < 2; ++km)
#pragma unroll
        for (int ct = 0; ct < 4; ++ct)
            offB[km][ct] = swz((wc * 128 + ct * 32 + ln) * 4 + km * 2 + kh);

    // A fragment global base (uint4 units): kc-plane stride is BATCH rows
    const int mbase = m0 + wr * 64 + ln;

    v16i acc[2][4];
#pragma unroll
    for (int rt = 0; rt < 2; ++rt)
#pragma unroll
        for (int ct = 0; ct < 4; ++ct)
#pragma unroll
            for (int e = 0; e < 16; ++e) acc[rt][ct][e] = 0;

    // prologue: prime 2 B tiles; wait only tile 0 (tile 1 stays in flight)
    STAGE_B(0, 0);
    STAGE_B(1, 64);
    asm volatile("s_waitcnt vmcnt(4)" ::: "memory");
    __builtin_amdgcn_s_barrier();

    int buf = 0;
    for (int s = 0; s < NSTEP; ++s) {
        // ---- A fragments: direct, coalesced, L1/L2-resident (issued FIRST
        // so their completion wait is vmcnt(4), not vmcnt(0)) --------------
        uint4 af[2][2];
#pragma unroll
        for (int km = 0; km < 2; ++km)
#pragma unroll
            for (int rt = 0; rt < 2; ++rt)
                af[km][rt] = aT4[(size_t)(s * 4 + km * 2 + kh) * BATCH
                                 + mbase + rt * 32];

        if (s + 2 < NSTEP) {                       // issue B k(s+2); in flight
            int nb = buf + 2; if (nb >= NBUF) nb -= NBUF;
            STAGE_B(nb, (s + 2) * 64);
        }

        uint4 bf[2][4];
#pragma unroll
        for (int km = 0; km < 2; ++km)
#pragma unroll
            for (int ct = 0; ct < 4; ++ct) bf[km][ct] = sB[buf][offB[km][ct]];

        // ---- two MFMA clusters, setprio-wrapped (T5) ----------------------
        __builtin_amdgcn_s_setprio(1);
#pragma unroll
        for (int rt = 0; rt < 2; ++rt)
#pragma unroll
            for (int ct = 0; ct < 4; ++ct)
                acc[rt][ct] = __builtin_amdgcn_mfma_i32_32x32x32_i8(
                    *(v4i*)&af[0][rt], *(v4i*)&bf[0][ct], acc[rt][ct], 0, 0, 0);
        __builtin_amdgcn_s_setprio(0);
        __builtin_amdgcn_s_setprio(1);
#pragma unroll
        for (int rt = 0; rt < 2; ++rt)
#pragma unroll
            for (int ct = 0; ct < 4; ++ct)
                acc[rt][ct] = __builtin_amdgcn_mfma_i32_32x32x32_i8(
                    *(v4i*)&af[1][rt], *(v4i*)&bf[1][ct], acc[rt][ct], 0, 0, 0);
        __builtin_amdgcn_s_setprio(0);

        if (s < NSTEP - 1) {
            // counted drain: B k(s+1) done; B k(s+2) (4 loads) stays in
            // flight. lgkmcnt(0): our ds_reads of buf done before others
            // restage it (step s+1 stages buf[(s+3)%3] == buf).
            if (s < NSTEP - 2)
                asm volatile("s_waitcnt vmcnt(4) lgkmcnt(0)" ::: "memory");
            else
                asm volatile("s_waitcnt vmcnt(0) lgkmcnt(0)" ::: "memory");
            __builtin_amdgcn_s_barrier();
        }
        buf = buf + 1 == NBUF ? 0 : buf + 1;
    }

    // ---- epilogue: packed argmin, exact tie-break (verified r6/r7) ---------
    int sk[4];
#pragma unroll
    for (int ct = 0; ct < 4; ++ct) sk[ct] = sumk[n0 + wc * 128 + ct * 32 + ln];

#pragma unroll
    for (int rt = 0; rt < 2; ++rt) {
#pragma unroll
        for (int r = 0; r < 16; ++r) {
            // verified C/D map: col = lane&31, row = (r&3)+8*(r>>2)+4*(lane>>5)
            const int qrow = m0 + wr * 64 + rt * 32 + (r & 3) + 8 * (r >> 2) + 4 * kh;
            uint32_t bmin = 0xFFFFFFFFu;
#pragma unroll
            for (int ct = 0; ct < 4; ++ct) {
                uint32_t dist = (uint32_t)(sk[ct] - 2 * acc[rt][ct][r] + 2048);
                uint32_t col  = (uint32_t)(n0 + wc * 128 + ct * 32 + ln);
                bmin = min(bmin, (dist << 16) | col);
            }
#pragma unroll
            for (int off = 1; off < 32; off <<= 1)   // reduce over 32 cols
                bmin = min(bmin, (uint32_t)__shfl_xor((int)bmin, off, 64));
            if (ln == 0) atomicMin(&best[qrow], bmin);
        }
    }
}

// ---- best[q] -> gather values row ------------------------------------------
__global__ void finalize_kernel(const uint32_t* __restrict__ best,
                                const float* __restrict__ values,
                                float* __restrict__ out) {
    const int qy  = blockIdx.x;
    const int idx = (int)(best[qy] & 0xFFFFu);
    const float4* v4 = reinterpret_cast<const float4*>(values) + (size_t)idx * 256;
    float4* o4 = reinterpret_cast<float4*>(out) + (size_t)qy * 256;
    o4[threadIdx.x] = v4[threadIdx.x];
}

// ===========================================================================
// Fallback (round-5 VALU scan, 401 us) if ws_size can't hold i8 keys
// ===========================================================================
#define KCHUNK 256
#define NSPLIT (CAPACITY / KCHUNK)

__device__ __forceinline__ uint32_t pack_word(const int4* __restrict__ p) {
    uint32_t word = 0;
#pragma unroll
    for (int j = 0; j < 8; ++j) {
        int4 v = p[j];
        word |= (uint32_t)(v.x & 1) << (4 * j + 0);
        word |= (uint32_t)(v.y & 1) << (4 * j + 1);
        word |= (uint32_t)(v.z & 1) << (4 * j + 2);
        word |= (uint32_t)(v.w & 1) << (4 * j + 3);
    }
    return word;
}

__global__ void pack_bits_kernel(const int* __restrict__ in,
                                 uint32_t* __restrict__ out, int nwords) {
    int w = blockIdx.x * blockDim.x + threadIdx.x;
    if (w >= nwords) return;
    out[w] = pack_word(reinterpret_cast<const int4*>(in) + (size_t)w * 8);
}

__launch_bounds__(256, 4)
__global__ void scan_kernel(const uint32_t* __restrict__ qpack,
                            const uint32_t* __restrict__ kpack,
                            uint32_t* __restrict__ best) {
    const int t      = threadIdx.x;
    const int lane   = t & 63;
    const int wid    = t >> 6;
    const int ksplit = blockIdx.x & (NSPLIT - 1);
    const int qgb    = blockIdx.x >> 8;
    const int query  = qgb * 256 + wid * 64 + lane;

    uint32_t q[32];
    const uint4* qp4 = reinterpret_cast<const uint4*>(qpack + (size_t)query * 32);
#pragma unroll
    for (int j = 0; j < 8; ++j) {
        uint4 v = qp4[j];
        q[4 * j + 0] = v.x; q[4 * j + 1] = v.y;
        q[4 * j + 2] = v.z; q[4 * j + 3] = v.w;
    }
    uint32_t bst = 0xFFFFFFFFu;
    const int k0 = ksplit * KCHUNK;
#pragma unroll 2
    for (int k = k0; k < k0 + KCHUNK; ++k) {
        const uint4* kw4 = reinterpret_cast<const uint4*>(kpack + (size_t)k * 32);
        uint32_t dist = 0;
#pragma unroll
        for (int j = 0; j < 8; ++j) {
            uint4 kv = kw4[j];
            dist += __popc(kv.x ^ q[4 * j + 0]);
            dist += __popc(kv.y ^ q[4 * j + 1]);
            dist += __popc(kv.z ^ q[4 * j + 2]);
            dist += __popc(kv.w ^ q[4 * j + 3]);
        }
        bst = min(bst, (dist << 16) | (uint32_t)k);
    }
    atomicMin(&best[query], bst);
}

// ===========================================================================
extern "C" void kernel_launch(void* const* d_in, const int* in_sizes, int n_in,
                              void* d_out, int out_size, void* d_ws, size_t ws_size,
                              hipStream_t stream) {
    const int*   query  = (const int*)d_in[0];   // [2048, 1024] int32 0/1
    const int*   keys   = (const int*)d_in[1];   // [65536, 1024] int32 0/1
    const float* values = (const float*)d_in[2]; // [65536, 1024] f32
    float*       out    = (float*)d_out;         // [2048, 1024] f32
    char* ws = (char*)d_ws;

    const size_t need = 2097152ULL + 67108864ULL + 262144ULL + 8192ULL;
    if (ws_size >= need) {
        uint32_t* qT  = (uint32_t*)ws;                           // 2 MB blocked-T
        unsigned char* ki8 = (unsigned char*)(ws + 2097152);     // 64 MB
        int* sumk = (int*)(ws + 2097152 + 67108864);             // 256 KB
        uint32_t* best = (uint32_t*)(ws + 2097152 + 67108864 + 262144);

        init_best_kernel<<<BATCH / 256, 256, 0, stream>>>(best);
        prep_qT_kernel<<<BATCH,    256, 0, stream>>>(query, qT);
        prep_i8_kernel<<<CAPACITY, 256, 0, stream>>>(keys, ki8, sumk);
        gemm_scan_kernel<<<16 * 256, 256, 0, stream>>>(
            reinterpret_cast<const uint4*>(qT), ki8, sumk, best);
        finalize_kernel<<<BATCH, 256, 0, stream>>>(best, values, out);
    } else {
        uint32_t* qpack = (uint32_t*)ws;                         // 256 KB
        uint32_t* kpack = (uint32_t*)(ws + 262144);              // 8 MB
        uint32_t* best  = (uint32_t*)(ws + 262144 + 8388608);    // 8 KB

        init_best_kernel<<<BATCH / 256, 256, 0, stream>>>(best);
        pack_bits_kernel<<<BATCH * 32 / 256, 256, 0, stream>>>(query, qpack, BATCH * 32);
        pack_bits_kernel<<<CAPACITY * 32 / 256, 256, 0, stream>>>(keys, kpack, CAPACITY * 32);
        scan_kernel<<<8 * NSPLIT, 256, 0, stream>>>(qpack, kpack, best);
        finalize_kernel<<<BATCH, 256, 0, stream>>>(best, values, out);
    }
}

// Round 9
// 265.316 us; speedup vs baseline: 2.0623x; 1.0005x over previous
//
#include <hip/hip_runtime.h>
#include <stdint.h>

typedef int v4i  __attribute__((ext_vector_type(4)));
typedef int v16i __attribute__((ext_vector_type(16)));

#define CAPACITY  65536
#define BATCH     2048
#define KBITS     1024
#define NSTEP     16      // K-steps of 64 bytes
#define NBUF      3       // triple-buffered B LDS

// ===========================================================================
// MFMA path: dist(q,k) = sumq + sumk - 2*dot(q,k). sumq is constant per query
// row -> drop it; rank by packed ((sumk - 2*dot + 2048)<<16) | key_idx, exact
// (0 <= biased dist <= 3072 < 2^16), reproduces first-max argmax.
// A (queries) is read per-fragment straight from a blocked-transposed global
// layout (L1/L2-resident); only B (keys) goes through LDS.
// ===========================================================================

// ---- queries: bits -> i8, blocked-transposed qT[k/16][m][16] ----------------
// Fragment load for mfma A-operand (lane l: row=l&31, k=(l>>5)*16..+16) is
// then one coalesced global_load_dwordx4 (32 lanes x contiguous 16B).
__global__ void prep_qT_kernel(const int* __restrict__ in,
                               uint32_t* __restrict__ outT) {
    const int row = blockIdx.x, t = threadIdx.x;   // t covers bits 4t..4t+3
    int4 v = reinterpret_cast<const int4*>(in)[(size_t)row * 256 + t];
    uint32_t b = (uint32_t)(v.x & 1)        | ((uint32_t)(v.y & 1) << 8) |
                 ((uint32_t)(v.z & 1) << 16) | ((uint32_t)(v.w & 1) << 24);
    // kc = t>>2 (16-byte k-chunk), u32 slot within chunk = t&3
    outT[(size_t)(t >> 2) * (BATCH * 4) + (size_t)row * 4 + (t & 3)] = b;
}

// ---- keys: bits -> i8 row-major, plus per-row bit count ---------------------
__global__ void prep_i8_kernel(const int* __restrict__ in,
                               unsigned char* __restrict__ out8,
                               int* __restrict__ sums) {
    const int row = blockIdx.x, t = threadIdx.x;
    int4 v = reinterpret_cast<const int4*>(in)[(size_t)row * 256 + t];
    uint32_t b = (uint32_t)(v.x & 1)        | ((uint32_t)(v.y & 1) << 8) |
                 ((uint32_t)(v.z & 1) << 16) | ((uint32_t)(v.w & 1) << 24);
    reinterpret_cast<uint32_t*>(out8)[(size_t)row * 256 + t] = b;
    int s = (v.x & 1) + (v.y & 1) + (v.z & 1) + (v.w & 1);
    for (int off = 32; off; off >>= 1) s += __shfl_xor(s, off, 64);
    __shared__ int ws4[4];
    if ((t & 63) == 0) ws4[t >> 6] = s;
    __syncthreads();
    if (t == 0) sums[row] = ws4[0] + ws4[1] + ws4[2] + ws4[3];
}

__global__ void init_best_kernel(uint32_t* __restrict__ best) {
    best[blockIdx.x * 256 + threadIdx.x] = 0xFFFFFFFFu;
}

// Involutive 16B-chunk swizzle within a [rows][64B] tile (idx = row*4+chunk):
// self-inverse, spreads consecutive rows across bank groups (read floor).
// global_load_lds sources pre-swizzled with the SAME function, LDS linear.
__device__ __forceinline__ int swz(int idx) { return idx ^ ((idx >> 3) & 7); }

// ---- GEMM + fused argmin ---------------------------------------------------
// Block tile 128(M) x 256(N), K-step 64 B, 4 waves as 2x2, each wave 2x4
// tiles of mfma_i32_32x32x32_i8. A fragments direct from global (qT);
// B staged via global_load_lds into triple-buffered LDS with counted vmcnt.
// Per step: af loads issued FIRST (so compiler's af-wait vmcnt(4) leaves the
// 4 B-stage loads of k(s+2) in flight), then STAGE, ds_reads, and two
// setprio-wrapped 8-MFMA clusters (T5: role-split for the CU scheduler).
__launch_bounds__(256, 2)
__global__ void gemm_scan_kernel(const uint4* __restrict__ aT4,
                                 const unsigned char* __restrict__ ki8,
                                 const int* __restrict__ sumk,
                                 uint32_t* __restrict__ best) {
    __shared__ uint4 sB[NBUF][1024];   // 256 rows x 4 chunks -> 48 KB

    const int t    = threadIdx.x;
    const int lane = t & 63, wid = t >> 6;
    const int wr   = wid >> 1, wc = wid & 1;      // wave grid 2x2
    const int ln   = lane & 31, kh = lane >> 5;   // mfma row, k-half

    // XCD-pinned tile order: xcd = blockIdx&7 owns 32 ntiles, mtile innermost
    const int b     = blockIdx.x;
    const int slot  = b >> 3;
    const int ntile = (b & 7) * 32 + (slot >> 4);
    const int mtile = slot & 15;
    const int m0 = mtile * 128, n0 = ntile * 256;

    // B staging sources, pre-swizzled (swz is an involution; LDS dest linear)
    const unsigned char* bSrc[4];
#pragma unroll
    for (int i = 0; i < 4; ++i) {
        int idx = swz(wid * 256 + i * 64 + lane);
        bSrc[i] = ki8 + (size_t)(n0 + (idx >> 2)) * KBITS + (idx & 3) * 16;
    }
    auto STAGE_B = [&](int buf, int kc) {          // 4 x global_load_lds(16B)
#pragma unroll
        for (int i = 0; i < 4; ++i)
            __builtin_amdgcn_global_load_lds(
                (const __attribute__((address_space(1))) void*)(bSrc[i] + kc),
                (__attribute__((address_space(3))) void*)&sB[buf][wid * 256 + i * 64],
                16, 0, 0);
    };

    // B fragment LDS offsets (K-invariant)
    int offB[2][4];
#pragma unroll
    for (int km = 0; km < 2; ++km)
#pragma unroll
        for (int ct = 0; ct < 4; ++ct)
            offB[km][ct] = swz((wc * 128 + ct * 32 + ln) * 4 + km * 2 + kh);

    // A fragment global base (uint4 units): kc-plane stride is BATCH rows
    const int mbase = m0 + wr * 64 + ln;

    v16i acc[2][4];
#pragma unroll
    for (int rt = 0; rt < 2; ++rt)
#pragma unroll
        for (int ct = 0; ct < 4; ++ct)
#pragma unroll
            for (int e = 0; e < 16; ++e) acc[rt][ct][e] = 0;

    // prologue: prime 2 B tiles; wait only tile 0 (tile 1 stays in flight)
    STAGE_B(0, 0);
    STAGE_B(1, 64);
    asm volatile("s_waitcnt vmcnt(4)" ::: "memory");
    __builtin_amdgcn_s_barrier();

    int buf = 0;
    for (int s = 0; s < NSTEP; ++s) {
        // ---- A fragments: direct, coalesced, L1/L2-resident (issued FIRST
        // so their completion wait is vmcnt(4), not vmcnt(0)) --------------
        uint4 af[2][2];
#pragma unroll
        for (int km = 0; km < 2; ++km)
#pragma unroll
            for (int rt = 0; rt < 2; ++rt)
                af[km][rt] = aT4[(size_t)(s * 4 + km * 2 + kh) * BATCH
                                 + mbase + rt * 32];

        if (s + 2 < NSTEP) {                       // issue B k(s+2); in flight
            int nb = buf + 2; if (nb >= NBUF) nb -= NBUF;
            STAGE_B(nb, (s + 2) * 64);
        }

        uint4 bf[2][4];
#pragma unroll
        for (int km = 0; km < 2; ++km)
#pragma unroll
            for (int ct = 0; ct < 4; ++ct) bf[km][ct] = sB[buf][offB[km][ct]];

        // ---- two MFMA clusters, setprio-wrapped (T5) ----------------------
        __builtin_amdgcn_s_setprio(1);
#pragma unroll
        for (int rt = 0; rt < 2; ++rt)
#pragma unroll
            for (int ct = 0; ct < 4; ++ct)
                acc[rt][ct] = __builtin_amdgcn_mfma_i32_32x32x32_i8(
                    *(v4i*)&af[0][rt], *(v4i*)&bf[0][ct], acc[rt][ct], 0, 0, 0);
        __builtin_amdgcn_s_setprio(0);
        __builtin_amdgcn_s_setprio(1);
#pragma unroll
        for (int rt = 0; rt < 2; ++rt)
#pragma unroll
            for (int ct = 0; ct < 4; ++ct)
                acc[rt][ct] = __builtin_amdgcn_mfma_i32_32x32x32_i8(
                    *(v4i*)&af[1][rt], *(v4i*)&bf[1][ct], acc[rt][ct], 0, 0, 0);
        __builtin_amdgcn_s_setprio(0);

        if (s < NSTEP - 1) {
            // counted drain: B k(s+1) done; B k(s+2) (4 loads) stays in
            // flight. lgkmcnt(0): our ds_reads of buf done before others
            // restage it (step s+1 stages buf[(s+3)%3] == buf).
            if (s < NSTEP - 2)
                asm volatile("s_waitcnt vmcnt(4) lgkmcnt(0)" ::: "memory");
            else
                asm volatile("s_waitcnt vmcnt(0) lgkmcnt(0)" ::: "memory");
            __builtin_amdgcn_s_barrier();
        }
        buf = buf + 1 == NBUF ? 0 : buf + 1;
    }

    // ---- epilogue: packed argmin, exact tie-break (verified r6/r7) ---------
    int sk[4];
#pragma unroll
    for (int ct = 0; ct < 4; ++ct) sk[ct] = sumk[n0 + wc * 128 + ct * 32 + ln];

#pragma unroll
    for (int rt = 0; rt < 2; ++rt) {
#pragma unroll
        for (int r = 0; r < 16; ++r) {
            // verified C/D map: col = lane&31, row = (r&3)+8*(r>>2)+4*(lane>>5)
            const int qrow = m0 + wr * 64 + rt * 32 + (r & 3) + 8 * (r >> 2) + 4 * kh;
            uint32_t bmin = 0xFFFFFFFFu;
#pragma unroll
            for (int ct = 0; ct < 4; ++ct) {
                uint32_t dist = (uint32_t)(sk[ct] - 2 * acc[rt][ct][r] + 2048);
                uint32_t col  = (uint32_t)(n0 + wc * 128 + ct * 32 + ln);
                bmin = min(bmin, (dist << 16) | col);
            }
#pragma unroll
            for (int off = 1; off < 32; off <<= 1)   // reduce over 32 cols
                bmin = min(bmin, (uint32_t)__shfl_xor((int)bmin, off, 64));
            if (ln == 0) atomicMin(&best[qrow], bmin);
        }
    }
}

// ---- best[q] -> gather values row ------------------------------------------
__global__ void finalize_kernel(const uint32_t* __restrict__ best,
                                const float* __restrict__ values,
                                float* __restrict__ out) {
    const int qy  = blockIdx.x;
    const int idx = (int)(best[qy] & 0xFFFFu);
    const float4* v4 = reinterpret_cast<const float4*>(values) + (size_t)idx * 256;
    float4* o4 = reinterpret_cast<float4*>(out) + (size_t)qy * 256;
    o4[threadIdx.x] = v4[threadIdx.x];
}

// ===========================================================================
// Fallback (round-5 VALU scan, 401 us) if ws_size can't hold i8 keys
// ===========================================================================
#define KCHUNK 256
#define NSPLIT (CAPACITY / KCHUNK)

__device__ __forceinline__ uint32_t pack_word(const int4* __restrict__ p) {
    uint32_t word = 0;
#pragma unroll
    for (int j = 0; j < 8; ++j) {
        int4 v = p[j];
        word |= (uint32_t)(v.x & 1) << (4 * j + 0);
        word |= (uint32_t)(v.y & 1) << (4 * j + 1);
        word |= (uint32_t)(v.z & 1) << (4 * j + 2);
        word |= (uint32_t)(v.w & 1) << (4 * j + 3);
    }
    return word;
}

__global__ void pack_bits_kernel(const int* __restrict__ in,
                                 uint32_t* __restrict__ out, int nwords) {
    int w = blockIdx.x * blockDim.x + threadIdx.x;
    if (w >= nwords) return;
    out[w] = pack_word(reinterpret_cast<const int4*>(in) + (size_t)w * 8);
}

__launch_bounds__(256, 4)
__global__ void scan_kernel(const uint32_t* __restrict__ qpack,
                            const uint32_t* __restrict__ kpack,
                            uint32_t* __restrict__ best) {
    const int t      = threadIdx.x;
    const int lane   = t & 63;
    const int wid    = t >> 6;
    const int ksplit = blockIdx.x & (NSPLIT - 1);
    const int qgb    = blockIdx.x >> 8;
    const int query  = qgb * 256 + wid * 64 + lane;

    uint32_t q[32];
    const uint4* qp4 = reinterpret_cast<const uint4*>(qpack + (size_t)query * 32);
#pragma unroll
    for (int j = 0; j < 8; ++j) {
        uint4 v = qp4[j];
        q[4 * j + 0] = v.x; q[4 * j + 1] = v.y;
        q[4 * j + 2] = v.z; q[4 * j + 3] = v.w;
    }
    uint32_t bst = 0xFFFFFFFFu;
    const int k0 = ksplit * KCHUNK;
#pragma unroll 2
    for (int k = k0; k < k0 + KCHUNK; ++k) {
        const uint4* kw4 = reinterpret_cast<const uint4*>(kpack + (size_t)k * 32);
        uint32_t dist = 0;
#pragma unroll
        for (int j = 0; j < 8; ++j) {
            uint4 kv = kw4[j];
            dist += __popc(kv.x ^ q[4 * j + 0]);
            dist += __popc(kv.y ^ q[4 * j + 1]);
            dist += __popc(kv.z ^ q[4 * j + 2]);
            dist += __popc(kv.w ^ q[4 * j + 3]);
        }
        bst = min(bst, (dist << 16) | (uint32_t)k);
    }
    atomicMin(&best[query], bst);
}

// ===========================================================================
extern "C" void kernel_launch(void* const* d_in, const int* in_sizes, int n_in,
                              void* d_out, int out_size, void* d_ws, size_t ws_size,
                              hipStream_t stream) {
    const int*   query  = (const int*)d_in[0];   // [2048, 1024] int32 0/1
    const int*   keys   = (const int*)d_in[1];   // [65536, 1024] int32 0/1
    const float* values = (const float*)d_in[2]; // [65536, 1024] f32
    float*       out    = (float*)d_out;         // [2048, 1024] f32
    char* ws = (char*)d_ws;

    const size_t need = 2097152ULL + 67108864ULL + 262144ULL + 8192ULL;
    if (ws_size >= need) {
        uint32_t* qT  = (uint32_t*)ws;                           // 2 MB blocked-T
        unsigned char* ki8 = (unsigned char*)(ws + 2097152);     // 64 MB
        int* sumk = (int*)(ws + 2097152 + 67108864);             // 256 KB
        uint32_t* best = (uint32_t*)(ws + 2097152 + 67108864 + 262144);

        init_best_kernel<<<BATCH / 256, 256, 0, stream>>>(best);
        prep_qT_kernel<<<BATCH,    256, 0, stream>>>(query, qT);
        prep_i8_kernel<<<CAPACITY, 256, 0, stream>>>(keys, ki8, sumk);
        gemm_scan_kernel<<<16 * 256, 256, 0, stream>>>(
            reinterpret_cast<const uint4*>(qT), ki8, sumk, best);
        finalize_kernel<<<BATCH, 256, 0, stream>>>(best, values, out);
    } else {
        uint32_t* qpack = (uint32_t*)ws;                         // 256 KB
        uint32_t* kpack = (uint32_t*)(ws + 262144);              // 8 MB
        uint32_t* best  = (uint32_t*)(ws + 262144 + 8388608);    // 8 KB

        init_best_kernel<<<BATCH / 256, 256, 0, stream>>>(best);
        pack_bits_kernel<<<BATCH * 32 / 256, 256, 0, stream>>>(query, qpack, BATCH * 32);
        pack_bits_kernel<<<CAPACITY * 32 / 256, 256, 0, stream>>>(keys, kpack, CAPACITY * 32);
        scan_kernel<<<8 * NSPLIT, 256, 0, stream>>>(qpack, kpack, best);
        finalize_kernel<<<BATCH, 256, 0, stream>>>(best, values, out);
    }
}

// Round 10
// 265.018 us; speedup vs baseline: 2.0646x; 1.0011x over previous
//
#include <hip/hip_runtime.h>
#include <stdint.h>

typedef int v4i  __attribute__((ext_vector_type(4)));
typedef int v16i __attribute__((ext_vector_type(16)));

#define CAPACITY  65536
#define BATCH     2048
#define KBITS     1024
#define NSTEP     16      // K-steps of 64 bytes
#define NBUF      3       // triple-buffered B LDS

// ===========================================================================
// MFMA path: dist(q,k) = sumq + sumk - 2*dot(q,k). sumq is constant per query
// row -> drop it; rank by packed ((sumk - 2*dot + 2048)<<16) | key_idx, exact
// (0 <= biased dist <= 3072 < 2^16), reproduces first-max argmax.
// A (queries) is read per-fragment straight from a blocked-transposed global
// layout (L1/L2-resident); only B (keys) goes through LDS.
// ===========================================================================

// ---- queries: bits -> i8, blocked-transposed qT[k/16][m][16] ----------------
// Fragment load for mfma A-operand (lane l: row=l&31, k=(l>>5)*16..+16) is
// then one coalesced global_load_dwordx4 (32 lanes x contiguous 16B).
__global__ void prep_qT_kernel(const int* __restrict__ in,
                               uint32_t* __restrict__ outT) {
    const int row = blockIdx.x, t = threadIdx.x;   // t covers bits 4t..4t+3
    int4 v = reinterpret_cast<const int4*>(in)[(size_t)row * 256 + t];
    uint32_t b = (uint32_t)(v.x & 1)        | ((uint32_t)(v.y & 1) << 8) |
                 ((uint32_t)(v.z & 1) << 16) | ((uint32_t)(v.w & 1) << 24);
    // kc = t>>2 (16-byte k-chunk), u32 slot within chunk = t&3
    outT[(size_t)(t >> 2) * (BATCH * 4) + (size_t)row * 4 + (t & 3)] = b;
}

// ---- keys: bits -> i8 row-major, plus per-row bit count ---------------------
__global__ void prep_i8_kernel(const int* __restrict__ in,
                               unsigned char* __restrict__ out8,
                               int* __restrict__ sums) {
    const int row = blockIdx.x, t = threadIdx.x;
    int4 v = reinterpret_cast<const int4*>(in)[(size_t)row * 256 + t];
    uint32_t b = (uint32_t)(v.x & 1)        | ((uint32_t)(v.y & 1) << 8) |
                 ((uint32_t)(v.z & 1) << 16) | ((uint32_t)(v.w & 1) << 24);
    reinterpret_cast<uint32_t*>(out8)[(size_t)row * 256 + t] = b;
    int s = (v.x & 1) + (v.y & 1) + (v.z & 1) + (v.w & 1);
    for (int off = 32; off; off >>= 1) s += __shfl_xor(s, off, 64);
    __shared__ int ws4[4];
    if ((t & 63) == 0) ws4[t >> 6] = s;
    __syncthreads();
    if (t == 0) sums[row] = ws4[0] + ws4[1] + ws4[2] + ws4[3];
}

__global__ void init_best_kernel(uint32_t* __restrict__ best) {
    best[blockIdx.x * 256 + threadIdx.x] = 0xFFFFFFFFu;
}

// Involutive 16B-chunk swizzle within a [rows][64B] tile (idx = row*4+chunk):
// self-inverse, spreads consecutive rows across bank groups (read floor).
// global_load_lds sources pre-swizzled with the SAME function, LDS linear.
__device__ __forceinline__ int swz(int idx) { return idx ^ ((idx >> 3) & 7); }

// ---- GEMM + fused argmin ---------------------------------------------------
// Block tile 128(M) x 256(N), K-step 64 B, 4 waves as 2x2, each wave 2x4
// tiles of mfma_i32_32x32x32_i8. A fragments direct from global (qT);
// B staged via global_load_lds into triple-buffered LDS with counted vmcnt.
// Per step: af loads issued FIRST (so compiler's af-wait vmcnt(4) leaves the
// 4 B-stage loads of k(s+2) in flight), then STAGE, ds_reads, and two
// setprio-wrapped 8-MFMA clusters (T5: role-split for the CU scheduler).
__launch_bounds__(256, 2)
__global__ void gemm_scan_kernel(const uint4* __restrict__ aT4,
                                 const unsigned char* __restrict__ ki8,
                                 const int* __restrict__ sumk,
                                 uint32_t* __restrict__ best) {
    __shared__ uint4 sB[NBUF][1024];   // 256 rows x 4 chunks -> 48 KB

    const int t    = threadIdx.x;
    const int lane = t & 63, wid = t >> 6;
    const int wr   = wid >> 1, wc = wid & 1;      // wave grid 2x2
    const int ln   = lane & 31, kh = lane >> 5;   // mfma row, k-half

    // XCD-pinned tile order: xcd = blockIdx&7 owns 32 ntiles, mtile innermost
    const int b     = blockIdx.x;
    const int slot  = b >> 3;
    const int ntile = (b & 7) * 32 + (slot >> 4);
    const int mtile = slot & 15;
    const int m0 = mtile * 128, n0 = ntile * 256;

    // B staging sources, pre-swizzled (swz is an involution; LDS dest linear)
    const unsigned char* bSrc[4];
#pragma unroll
    for (int i = 0; i < 4; ++i) {
        int idx = swz(wid * 256 + i * 64 + lane);
        bSrc[i] = ki8 + (size_t)(n0 + (idx >> 2)) * KBITS + (idx & 3) * 16;
    }
    auto STAGE_B = [&](int buf, int kc) {          // 4 x global_load_lds(16B)
#pragma unroll
        for (int i = 0; i < 4; ++i)
            __builtin_amdgcn_global_load_lds(
                (const __attribute__((address_space(1))) void*)(bSrc[i] + kc),
                (__attribute__((address_space(3))) void*)&sB[buf][wid * 256 + i * 64],
                16, 0, 0);
    };

    // B fragment LDS offsets (K-invariant)
    int offB[2][4];
#pragma unroll
    for (int km = 0; km < 2; ++km)
#pragma unroll
        for (int ct = 0; ct < 4; ++ct)
            offB[km][ct] = swz((wc * 128 + ct * 32 + ln) * 4 + km * 2 + kh);

    // A fragment global base (uint4 units): kc-plane stride is BATCH rows
    const int mbase = m0 + wr * 64 + ln;

    v16i acc[2][4];
#pragma unroll
    for (int rt = 0; rt < 2; ++rt)
#pragma unroll
        for (int ct = 0; ct < 4; ++ct)
#pragma unroll
            for (int e = 0; e < 16; ++e) acc[rt][ct][e] = 0;

    // prologue: prime 2 B tiles; wait only tile 0 (tile 1 stays in flight)
    STAGE_B(0, 0);
    STAGE_B(1, 64);
    asm volatile("s_waitcnt vmcnt(4)" ::: "memory");
    __builtin_amdgcn_s_barrier();

    int buf = 0;
    for (int s = 0; s < NSTEP; ++s) {
        // ---- A fragments: direct, coalesced, L1/L2-resident (issued FIRST
        // so their completion wait is vmcnt(4), not vmcnt(0)) --------------
        uint4 af[2][2];
#pragma unroll
        for (int km = 0; km < 2; ++km)
#pragma unroll
            for (int rt = 0; rt < 2; ++rt)
                af[km][rt] = aT4[(size_t)(s * 4 + km * 2 + kh) * BATCH
                                 + mbase + rt * 32];

        if (s + 2 < NSTEP) {                       // issue B k(s+2); in flight
            int nb = buf + 2; if (nb >= NBUF) nb -= NBUF;
            STAGE_B(nb, (s + 2) * 64);
        }

        uint4 bf[2][4];
#pragma unroll
        for (int km = 0; km < 2; ++km)
#pragma unroll
            for (int ct = 0; ct < 4; ++ct) bf[km][ct] = sB[buf][offB[km][ct]];

        // ---- two MFMA clusters, setprio-wrapped (T5) ----------------------
        __builtin_amdgcn_s_setprio(1);
#pragma unroll
        for (int rt = 0; rt < 2; ++rt)
#pragma unroll
            for (int ct = 0; ct < 4; ++ct)
                acc[rt][ct] = __builtin_amdgcn_mfma_i32_32x32x32_i8(
                    *(v4i*)&af[0][rt], *(v4i*)&bf[0][ct], acc[rt][ct], 0, 0, 0);
        __builtin_amdgcn_s_setprio(0);
        __builtin_amdgcn_s_setprio(1);
#pragma unroll
        for (int rt = 0; rt < 2; ++rt)
#pragma unroll
            for (int ct = 0; ct < 4; ++ct)
                acc[rt][ct] = __builtin_amdgcn_mfma_i32_32x32x32_i8(
                    *(v4i*)&af[1][rt], *(v4i*)&bf[1][ct], acc[rt][ct], 0, 0, 0);
        __builtin_amdgcn_s_setprio(0);

        if (s < NSTEP - 1) {
            // counted drain: B k(s+1) done; B k(s+2) (4 loads) stays in
            // flight. lgkmcnt(0): our ds_reads of buf done before others
            // restage it (step s+1 stages buf[(s+3)%3] == buf).
            if (s < NSTEP - 2)
                asm volatile("s_waitcnt vmcnt(4) lgkmcnt(0)" ::: "memory");
            else
                asm volatile("s_waitcnt vmcnt(0) lgkmcnt(0)" ::: "memory");
            __builtin_amdgcn_s_barrier();
        }
        buf = buf + 1 == NBUF ? 0 : buf + 1;
    }

    // ---- epilogue: packed argmin, exact tie-break (verified r6/r7) ---------
    int sk[4];
#pragma unroll
    for (int ct = 0; ct < 4; ++ct) sk[ct] = sumk[n0 + wc * 128 + ct * 32 + ln];

#pragma unroll
    for (int rt = 0; rt < 2; ++rt) {
#pragma unroll
        for (int r = 0; r < 16; ++r) {
            // verified C/D map: col = lane&31, row = (r&3)+8*(r>>2)+4*(lane>>5)
            const int qrow = m0 + wr * 64 + rt * 32 + (r & 3) + 8 * (r >> 2) + 4 * kh;
            uint32_t bmin = 0xFFFFFFFFu;
#pragma unroll
            for (int ct = 0; ct < 4; ++ct) {
                uint32_t dist = (uint32_t)(sk[ct] - 2 * acc[rt][ct][r] + 2048);
                uint32_t col  = (uint32_t)(n0 + wc * 128 + ct * 32 + ln);
                bmin = min(bmin, (dist << 16) | col);
            }
#pragma unroll
            for (int off = 1; off < 32; off <<= 1)   // reduce over 32 cols
                bmin = min(bmin, (uint32_t)__shfl_xor((int)bmin, off, 64));
            if (ln == 0) atomicMin(&best[qrow], bmin);
        }
    }
}

// ---- best[q] -> gather values row ------------------------------------------
__global__ void finalize_kernel(const uint32_t* __restrict__ best,
                                const float* __restrict__ values,
                                float* __restrict__ out) {
    const int qy  = blockIdx.x;
    const int idx = (int)(best[qy] & 0xFFFFu);
    const float4* v4 = reinterpret_cast<const float4*>(values) + (size_t)idx * 256;
    float4* o4 = reinterpret_cast<float4*>(out) + (size_t)qy * 256;
    o4[threadIdx.x] = v4[threadIdx.x];
}

// ===========================================================================
// Fallback (round-5 VALU scan, 401 us) if ws_size can't hold i8 keys
// ===========================================================================
#define KCHUNK 256
#define NSPLIT (CAPACITY / KCHUNK)

__device__ __forceinline__ uint32_t pack_word(const int4* __restrict__ p) {
    uint32_t word = 0;
#pragma unroll
    for (int j = 0; j < 8; ++j) {
        int4 v = p[j];
        word |= (uint32_t)(v.x & 1) << (4 * j + 0);
        word |= (uint32_t)(v.y & 1) << (4 * j + 1);
        word |= (uint32_t)(v.z & 1) << (4 * j + 2);
        word |= (uint32_t)(v.w & 1) << (4 * j + 3);
    }
    return word;
}

__global__ void pack_bits_kernel(const int* __restrict__ in,
                                 uint32_t* __restrict__ out, int nwords) {
    int w = blockIdx.x * blockDim.x + threadIdx.x;
    if (w >= nwords) return;
    out[w] = pack_word(reinterpret_cast<const int4*>(in) + (size_t)w * 8);
}

__launch_bounds__(256, 4)
__global__ void scan_kernel(const uint32_t* __restrict__ qpack,
                            const uint32_t* __restrict__ kpack,
                            uint32_t* __restrict__ best) {
    const int t      = threadIdx.x;
    const int lane   = t & 63;
    const int wid    = t >> 6;
    const int ksplit = blockIdx.x & (NSPLIT - 1);
    const int qgb    = blockIdx.x >> 8;
    const int query  = qgb * 256 + wid * 64 + lane;

    uint32_t q[32];
    const uint4* qp4 = reinterpret_cast<const uint4*>(qpack + (size_t)query * 32);
#pragma unroll
    for (int j = 0; j < 8; ++j) {
        uint4 v = qp4[j];
        q[4 * j + 0] = v.x; q[4 * j + 1] = v.y;
        q[4 * j + 2] = v.z; q[4 * j + 3] = v.w;
    }
    uint32_t bst = 0xFFFFFFFFu;
    const int k0 = ksplit * KCHUNK;
#pragma unroll 2
    for (int k = k0; k < k0 + KCHUNK; ++k) {
        const uint4* kw4 = reinterpret_cast<const uint4*>(kpack + (size_t)k * 32);
        uint32_t dist = 0;
#pragma unroll
        for (int j = 0; j < 8; ++j) {
            uint4 kv = kw4[j];
            dist += __popc(kv.x ^ q[4 * j + 0]);
            dist += __popc(kv.y ^ q[4 * j + 1]);
            dist += __popc(kv.z ^ q[4 * j + 2]);
            dist += __popc(kv.w ^ q[4 * j + 3]);
        }
        bst = min(bst, (dist << 16) | (uint32_t)k);
    }
    atomicMin(&best[query], bst);
}

// ===========================================================================
extern "C" void kernel_launch(void* const* d_in, const int* in_sizes, int n_in,
                              void* d_out, int out_size, void* d_ws, size_t ws_size,
                              hipStream_t stream) {
    const int*   query  = (const int*)d_in[0];   // [2048, 1024] int32 0/1
    const int*   keys   = (const int*)d_in[1];   // [65536, 1024] int32 0/1
    const float* values = (const float*)d_in[2]; // [65536, 1024] f32
    float*       out    = (float*)d_out;         // [2048, 1024] f32
    char* ws = (char*)d_ws;

    const size_t need = 2097152ULL + 67108864ULL + 262144ULL + 8192ULL;
    if (ws_size >= need) {
        uint32_t* qT  = (uint32_t*)ws;                           // 2 MB blocked-T
        unsigned char* ki8 = (unsigned char*)(ws + 2097152);     // 64 MB
        int* sumk = (int*)(ws + 2097152 + 67108864);             // 256 KB
        uint32_t* best = (uint32_t*)(ws + 2097152 + 67108864 + 262144);

        init_best_kernel<<<BATCH / 256, 256, 0, stream>>>(best);
        prep_qT_kernel<<<BATCH,    256, 0, stream>>>(query, qT);
        prep_i8_kernel<<<CAPACITY, 256, 0, stream>>>(keys, ki8, sumk);
        gemm_scan_kernel<<<16 * 256, 256, 0, stream>>>(
            reinterpret_cast<const uint4*>(qT), ki8, sumk, best);
        finalize_kernel<<<BATCH, 256, 0, stream>>>(best, values, out);
    } else {
        uint32_t* qpack = (uint32_t*)ws;                         // 256 KB
        uint32_t* kpack = (uint32_t*)(ws + 262144);              // 8 MB
        uint32_t* best  = (uint32_t*)(ws + 262144 + 8388608);    // 8 KB

        init_best_kernel<<<BATCH / 256, 256, 0, stream>>>(best);
        pack_bits_kernel<<<BATCH * 32 / 256, 256, 0, stream>>>(query, qpack, BATCH * 32);
        pack_bits_kernel<<<CAPACITY * 32 / 256, 256, 0, stream>>>(keys, kpack, CAPACITY * 32);
        scan_kernel<<<8 * NSPLIT, 256, 0, stream>>>(qpack, kpack, best);
        finalize_kernel<<<BATCH, 256, 0, stream>>>(best, values, out);
    }
}